// Round 7
// baseline (85.429 us; speedup 1.0000x reference)
//
#include <hip/hip_runtime.h>
#include <stdint.h>

typedef __attribute__((ext_vector_type(8))) short short8;
typedef __attribute__((ext_vector_type(4))) float f32x4;

#define NB 8
#define RROWS 3072
#define TROWS 1024
#define FEAT 256
#define FK 192
#define NCHUNK 8
#define CROWS 384               // 3072/8
#define CITERS 12               // 384/32
#define TT 128

#define GLOAD_LDS16(src, dst)                                                  \
  __builtin_amdgcn_global_load_lds(                                            \
      (const __attribute__((address_space(1))) void*)(src),                    \
      (__attribute__((address_space(3))) void*)(dst), 16, 0, 0)

static __device__ __forceinline__ unsigned short f2bf(float x) {
  union { float f; uint32_t u; } v; v.f = x;
  uint32_t u = v.u;
  uint32_t r = (u + 0x7fffu + ((u >> 16) & 1u)) >> 16;
  return (unsigned short)r;
}
static __device__ __forceinline__ float bf2f(unsigned short h) {
  union { uint32_t u; float f; } v; v.u = ((uint32_t)h) << 16;
  return v.f;
}
static __device__ __forceinline__ uint32_t pk2(float a, float b) {
  return (uint32_t)f2bf(a) | ((uint32_t)f2bf(b) << 16);
}

// ---------------- Stage 0: transpose weights to bf16 hi/lo [o][k] ------------
__global__ void wprep_kernel(const float* __restrict__ wf,
                             unsigned short* __restrict__ wth,
                             unsigned short* __restrict__ wtl) {
  const int o = blockIdx.x, k = threadIdx.x;  // 256 blocks x 192 thr
  const float v = wf[(size_t)k * 256 + o];
  const unsigned short h = f2bf(v);
  wth[(size_t)o * FK + k] = h;
  wtl[(size_t)o * FK + k] = f2bf(v - bf2f(h));
}

// ---------------- Stage 1: patch-embed conv via MFMA (bf16x2 3-pass) ---------
// Grid: 32 images x 16 blocks (64 patches each) = 512 blocks = 2/CU.
__global__ __launch_bounds__(256, 2) void feat_kernel(
    const float* __restrict__ ref, const float* __restrict__ tgt,
    const unsigned short* __restrict__ wth, const unsigned short* __restrict__ wtl,
    unsigned short* __restrict__ rh, unsigned short* __restrict__ rl,
    unsigned short* __restrict__ th, unsigned short* __restrict__ tl) {
  __shared__ unsigned short Ah[64 * 256];  // rows 512B (24 granules used), swizzled
  __shared__ unsigned short Al[64 * 256];
  const int tid = threadIdx.x;
  const int img = blockIdx.x >> 4;   // 0..31
  const int blk = blockIdx.x & 15;   // patch-row pair (16 image rows)
  const int n = img >> 2, f = img & 3;
  const float* src = (f < 3) ? (ref + (size_t)(n * 3 + f) * (256 * 256 * 3))
                             : (tgt + (size_t)n * (256 * 256 * 3));
  const float* base = src + (size_t)blk * 16 * 768;

#pragma unroll
  for (int j = 0; j < 12; ++j) {
    const int f4 = tid + 256 * j;
    const int y  = f4 / 192;
    const int fl = (f4 - y * 192) * 4;      // flat col in row, multiple of 4
    const float4 v = *(const float4*)(base + (size_t)y * 768 + fl);
    const int p = ((y >> 3) << 5) + fl / 24;
    const int k = (y & 7) * 24 + fl % 24;
    const int byterow = k * 2;              // multiple of 8
    const int gr  = (byterow >> 4) ^ (p & 7);
    const int off = byterow & 15;           // 0 or 8
    const unsigned short h0 = f2bf(v.x), h1 = f2bf(v.y);
    const unsigned short h2 = f2bf(v.z), h3 = f2bf(v.w);
    uint2 hw, lw;
    hw.x = (uint32_t)h0 | ((uint32_t)h1 << 16);
    hw.y = (uint32_t)h2 | ((uint32_t)h3 << 16);
    lw.x = (uint32_t)f2bf(v.x - bf2f(h0)) | ((uint32_t)f2bf(v.y - bf2f(h1)) << 16);
    lw.y = (uint32_t)f2bf(v.z - bf2f(h2)) | ((uint32_t)f2bf(v.w - bf2f(h3)) << 16);
    *(uint2*)((char*)Ah + p * 512 + gr * 16 + off) = hw;
    *(uint2*)((char*)Al + p * 512 + gr * 16 + off) = lw;
  }
  __syncthreads();

  const int w = tid >> 6, lane = tid & 63, lr = lane & 15, kc = lane >> 4;
  const size_t base_row = (f < 3) ? ((size_t)n * RROWS + (size_t)f * 1024 + blk * 64)
                                  : ((size_t)n * TROWS + blk * 64);
  unsigned short* dh = (f < 3) ? rh : th;
  unsigned short* dl = (f < 3) ? rl : tl;

#pragma unroll
  for (int ot = 0; ot < 4; ++ot) {
    const int otile = w + 4 * ot;
    short8 bh[6], bl[6];
#pragma unroll
    for (int c = 0; c < 6; ++c) {
      const size_t boff = (size_t)(otile * 16 + lr) * FK + c * 32 + kc * 8;
      bh[c] = *(const short8*)(wth + boff);
      bl[c] = *(const short8*)(wtl + boff);
    }
#pragma unroll
    for (int pt = 0; pt < 4; ++pt) {
      f32x4 acc = {0.f, 0.f, 0.f, 0.f};
      const char* arow_h = (const char*)Ah + (pt * 16 + lr) * 512;
      const char* arow_l = (const char*)Al + (pt * 16 + lr) * 512;
      const int sw = (lr & 7) << 4;
#pragma unroll
      for (int c = 0; c < 6; ++c) {
        const int aoff = ((c * 4 + kc) << 4) ^ sw;
        const short8 ah = *(const short8*)(arow_h + aoff);
        const short8 al = *(const short8*)(arow_l + aoff);
        acc = __builtin_amdgcn_mfma_f32_16x16x32_bf16(ah, bh[c], acc, 0, 0, 0);
        acc = __builtin_amdgcn_mfma_f32_16x16x32_bf16(al, bh[c], acc, 0, 0, 0);
        acc = __builtin_amdgcn_mfma_f32_16x16x32_bf16(ah, bl[c], acc, 0, 0, 0);
      }
#pragma unroll
      for (int i = 0; i < 4; ++i) {
        const size_t P = base_row + pt * 16 + 4 * kc + i;
        const float v = acc[i];
        const unsigned short h = f2bf(v);
        dh[P * 256 + otile * 16 + lr] = h;
        dl[P * 256 + otile * 16 + lr] = f2bf(v - bf2f(h));
      }
    }
  }
}

// ---------------- Stage 2a: flash partials, softmax pipelined vs QK ----------
// Grid: 512 blocks (8 XCD-pinned n x 8 t-tiles(128) x 8 chunks) = 2/CU.
// At iter it: STAGE(it+1) || QK(it) -> acc set X || softmax+PV(it-1) from set Y.
__global__ __launch_bounds__(256, 2) void flash_kernel(
    const unsigned short* __restrict__ rh, const unsigned short* __restrict__ rl,
    const unsigned short* __restrict__ th, const unsigned short* __restrict__ tl,
    const float* __restrict__ labels, float* __restrict__ part) {
  __shared__ unsigned short kh[2][8192], kl[2][8192];

  const int tid = threadIdx.x;
  const int bid = blockIdx.x;
  const int n   = bid & 7;
  const int tmp = bid >> 3;
  const int tt  = tmp >> 3;                 // 0..7
  const int ch  = tmp & 7;                  // 0..7
  const int tbase = tt * TT;

  const int w = tid >> 6;
  const int lane = tid & 63, lr = lane & 15, kc = lane >> 4;
  const int rr = tid >> 5;
  const int cg = (tid & 31) ^ rr;

  const unsigned short* khs = rh + ((size_t)n * RROWS + ch * CROWS) * 256;
  const unsigned short* kls = rl + ((size_t)n * RROWS + ch * CROWS) * 256;
  const float* labsrc = labels + ((size_t)n * RROWS + ch * CROWS) * 16;

#define STAGE(buf, itv)                                                        \
  do {                                                                         \
    const int rbase_ = (itv) * 32;                                             \
    _Pragma("unroll") for (int s = 0; s < 4; ++s) {                            \
      const int row_ = s * 8 + rr;                                             \
      const size_t goff_ = (size_t)(rbase_ + row_) * 256 + cg * 8;             \
      GLOAD_LDS16(khs + goff_, (char*)kh[buf] + s * 4096 + w * 1024);          \
      GLOAD_LDS16(kls + goff_, (char*)kl[buf] + s * 4096 + w * 1024);          \
    }                                                                          \
  } while (0)

  // Q fragments: two 16-column sets per wave, hi/lo
  short8 qh0[8], ql0[8], qh1[8], ql1[8];
  {
    const size_t qr0 = (size_t)n * TROWS + tbase + 16 * w + lr;
    const size_t qr1 = qr0 + 64;
#pragma unroll
    for (int ks = 0; ks < 8; ++ks) {
      qh0[ks] = *(const short8*)(th + qr0 * 256 + kc * 8 + ks * 32);
      ql0[ks] = *(const short8*)(tl + qr0 * 256 + kc * 8 + ks * 32);
      qh1[ks] = *(const short8*)(th + qr1 * 256 + kc * 8 + ks * 32);
      ql1[ks] = *(const short8*)(tl + qr1 * 256 + kc * 8 + ks * 32);
    }
  }

  float m0 = -3.0e38f, l0 = 0.f, m1 = -3.0e38f, l1 = 0.f;
  f32x4 opv0 = {0.f, 0.f, 0.f, 0.f}, opv1 = {0.f, 0.f, 0.f, 0.f};
  const int swz = (lr & 7) << 4;

  // two named acc/label sets (static indexing only)
  f32x4 A00, A01, A10, A11, B00, B01, B10, B11;
  float lvA[8], lvB[8];

#define LOADLAB(lv, itv)                                                       \
  do {                                                                         \
    const int rbase_ = (itv) * 32;                                             \
    _Pragma("unroll") for (int j = 0; j < 8; ++j)                              \
        lv[j] = labsrc[(size_t)(rbase_ + 8 * kc + j) * 16 + lr];               \
  } while (0)

#define QK(c00, c01, c10, c11, itv)                                            \
  do {                                                                         \
    const char* kb_h = (const char*)kh[(itv) & 1];                             \
    const char* kb_l = (const char*)kl[(itv) & 1];                             \
    const char* r0h = kb_h + lr * 512;                                         \
    const char* r1h = kb_h + (16 + lr) * 512;                                  \
    const char* r0l = kb_l + lr * 512;                                         \
    const char* r1l = kb_l + (16 + lr) * 512;                                  \
    c00 = (f32x4){0.f, 0.f, 0.f, 0.f}; c01 = (f32x4){0.f, 0.f, 0.f, 0.f};     \
    c10 = (f32x4){0.f, 0.f, 0.f, 0.f}; c11 = (f32x4){0.f, 0.f, 0.f, 0.f};     \
    _Pragma("unroll") for (int ks = 0; ks < 8; ++ks) {                         \
      const int off = (ks * 64 + kc * 16) ^ swz;                               \
      const short8 ah0 = *(const short8*)(r0h + off);                          \
      const short8 al0 = *(const short8*)(r0l + off);                          \
      const short8 ah1 = *(const short8*)(r1h + off);                          \
      const short8 al1 = *(const short8*)(r1l + off);                          \
      c00 = __builtin_amdgcn_mfma_f32_16x16x32_bf16(ah0, qh0[ks], c00, 0, 0, 0);\
      c00 = __builtin_amdgcn_mfma_f32_16x16x32_bf16(al0, qh0[ks], c00, 0, 0, 0);\
      c00 = __builtin_amdgcn_mfma_f32_16x16x32_bf16(ah0, ql0[ks], c00, 0, 0, 0);\
      c01 = __builtin_amdgcn_mfma_f32_16x16x32_bf16(ah1, qh0[ks], c01, 0, 0, 0);\
      c01 = __builtin_amdgcn_mfma_f32_16x16x32_bf16(al1, qh0[ks], c01, 0, 0, 0);\
      c01 = __builtin_amdgcn_mfma_f32_16x16x32_bf16(ah1, ql0[ks], c01, 0, 0, 0);\
      c10 = __builtin_amdgcn_mfma_f32_16x16x32_bf16(ah0, qh1[ks], c10, 0, 0, 0);\
      c10 = __builtin_amdgcn_mfma_f32_16x16x32_bf16(al0, qh1[ks], c10, 0, 0, 0);\
      c10 = __builtin_amdgcn_mfma_f32_16x16x32_bf16(ah0, ql1[ks], c10, 0, 0, 0);\
      c11 = __builtin_amdgcn_mfma_f32_16x16x32_bf16(ah1, qh1[ks], c11, 0, 0, 0);\
      c11 = __builtin_amdgcn_mfma_f32_16x16x32_bf16(al1, qh1[ks], c11, 0, 0, 0);\
      c11 = __builtin_amdgcn_mfma_f32_16x16x32_bf16(ah1, ql1[ks], c11, 0, 0, 0);\
    }                                                                          \
  } while (0)

#define SM_PV(accA, accB, mS, lS, opvS, lu)                                    \
  do {                                                                         \
    float tmax = fmaxf(fmaxf(fmaxf(accA[0], accA[1]), fmaxf(accA[2], accA[3])),\
                       fmaxf(fmaxf(accB[0], accB[1]), fmaxf(accB[2], accB[3])));\
    tmax = fmaxf(tmax, __shfl_xor(tmax, 16));                                  \
    tmax = fmaxf(tmax, __shfl_xor(tmax, 32));                                  \
    const float mnew = fmaxf(mS, tmax);                                        \
    float e0[4], e1[4], ts = 0.f;                                              \
    _Pragma("unroll") for (int i = 0; i < 4; ++i) {                            \
      e0[i] = __expf(accA[i] - mnew);                                          \
      e1[i] = __expf(accB[i] - mnew);                                          \
      ts += e0[i] + e1[i];                                                     \
    }                                                                          \
    ts += __shfl_xor(ts, 16);                                                  \
    ts += __shfl_xor(ts, 32);                                                  \
    const float fc = __expf(mS - mnew);                                        \
    lS = lS * fc + ts;                                                         \
    mS = mnew;                                                                 \
    const uint32_t w0 = pk2(e0[0], e0[1]), w1 = pk2(e0[2], e0[3]);             \
    const uint32_t w2 = pk2(e1[0], e1[1]), w3 = pk2(e1[2], e1[3]);             \
    const uint32_t x0 = __shfl_xor(w0, 32), x1 = __shfl_xor(w1, 32);           \
    const uint32_t x2 = __shfl_xor(w2, 32), x3 = __shfl_xor(w3, 32);           \
    const bool hB = (lane & 32) != 0;                                          \
    const uint32_t n0 = hB ? x2 : w0, n1 = hB ? x3 : w1;                       \
    const uint32_t n2 = hB ? w2 : x0, n3 = hB ? w3 : x1;                       \
    const uint32_t y0 = __shfl_xor(n0, 16), y1 = __shfl_xor(n1, 16);           \
    const uint32_t y2 = __shfl_xor(n2, 16), y3 = __shfl_xor(n3, 16);           \
    const bool hA = (lane & 16) != 0;                                          \
    union { uint32_t u[4]; short8 s8; } pu;                                    \
    pu.u[0] = hA ? y2 : n0;                                                    \
    pu.u[1] = hA ? y3 : n1;                                                    \
    pu.u[2] = hA ? n2 : y0;                                                    \
    pu.u[3] = hA ? n3 : y1;                                                    \
    const float fi0 = __shfl(fc, 4 * kc + 0, 16);                              \
    const float fi1 = __shfl(fc, 4 * kc + 1, 16);                              \
    const float fi2 = __shfl(fc, 4 * kc + 2, 16);                              \
    const float fi3 = __shfl(fc, 4 * kc + 3, 16);                              \
    opvS[0] *= fi0; opvS[1] *= fi1; opvS[2] *= fi2; opvS[3] *= fi3;            \
    opvS = __builtin_amdgcn_mfma_f32_16x16x32_bf16(pu.s8, lu.s8, opvS, 0, 0, 0);\
  } while (0)

#define PACKLU(lu, lv)                                                         \
  union { uint32_t u[4]; short8 s8; } lu;                                      \
  lu.u[0] = pk2(lv[0], lv[1]); lu.u[1] = pk2(lv[2], lv[3]);                    \
  lu.u[2] = pk2(lv[4], lv[5]); lu.u[3] = pk2(lv[6], lv[7]);

  // prologue: tile 0 staged+computed, no softmax yet
  STAGE(0, 0);
  __syncthreads();
  LOADLAB(lvA, 0);
  STAGE(1, 1);
  QK(A00, A01, A10, A11, 0);
  __syncthreads();

  // steady: iters 1..10 as 5 unroll-2 pairs
  for (int k = 0; k < 5; ++k) {
    const int itB = 2 * k + 1;
    LOADLAB(lvB, itB);
    STAGE((itB + 1) & 1, itB + 1);
    QK(B00, B01, B10, B11, itB);
    {
      PACKLU(luA, lvA);
      SM_PV(A00, A01, m0, l0, opv0, luA);
      SM_PV(A10, A11, m1, l1, opv1, luA);
    }
    __syncthreads();
    const int itA = 2 * k + 2;
    LOADLAB(lvA, itA);
    STAGE((itA + 1) & 1, itA + 1);
    QK(A00, A01, A10, A11, itA);
    {
      PACKLU(luB, lvB);
      SM_PV(B00, B01, m0, l0, opv0, luB);
      SM_PV(B10, B11, m1, l1, opv1, luB);
    }
    __syncthreads();
  }

  // iter 11: last tile (no stage), then drain both softmax sets
  LOADLAB(lvB, 11);
  QK(B00, B01, B10, B11, 11);
  {
    PACKLU(luA, lvA);
    SM_PV(A00, A01, m0, l0, opv0, luA);
    SM_PV(A10, A11, m1, l1, opv1, luA);
  }
  {
    PACKLU(luB, lvB);
    SM_PV(B00, B01, m0, l0, opv0, luB);
    SM_PV(B10, B11, m1, l1, opv1, luB);
  }

  float* pb = part + ((size_t)(n * 8 + tt) * NCHUNK + ch) * (TT * 18);
#pragma unroll
  for (int i = 0; i < 4; ++i) {
    pb[(16 * w + 4 * kc + i) * 18 + 2 + lr] = opv0[i];
    pb[(64 + 16 * w + 4 * kc + i) * 18 + 2 + lr] = opv1[i];
  }
  if (kc == 0) {
    pb[(16 * w + lr) * 18] = m0;
    pb[(16 * w + lr) * 18 + 1] = l0;
    pb[(64 + 16 * w + lr) * 18] = m1;
    pb[(64 + 16 * w + lr) * 18 + 1] = l1;
  }
#undef STAGE
#undef QK
#undef SM_PV
#undef PACKLU
#undef LOADLAB
}

// ---------------- Stage 2b: combine chunk partials ---------------------------
// Grid: 8 n x 8 t-tiles x 2 halves = 128 blocks x 256 thr.
__global__ __launch_bounds__(256) void combine_kernel(
    const float* __restrict__ part, float* __restrict__ out) {
  const int tid = threadIdx.x;
  const int tw = tid >> 2, g = tid & 3;
  const int half = blockIdx.x & 1, tt = (blockIdx.x >> 1) & 7, n = blockIdx.x >> 4;
  const float* pb = part + (size_t)((n * 8 + tt) * NCHUNK) * (TT * 18) +
                    (half * 64 + tw) * 18;
  float M = -3.0e38f;
#pragma unroll
  for (int c = 0; c < NCHUNK; ++c) M = fmaxf(M, pb[c * TT * 18]);
  float L = 0.f, o0 = 0.f, o1 = 0.f, o2 = 0.f, o3 = 0.f;
#pragma unroll
  for (int c = 0; c < NCHUNK; ++c) {
    const float* p = pb + c * TT * 18;
    const float wgt = __expf(p[0] - M);
    L  = fmaf(p[1], wgt, L);
    o0 = fmaf(p[2 + 4 * g + 0], wgt, o0);
    o1 = fmaf(p[2 + 4 * g + 1], wgt, o1);
    o2 = fmaf(p[2 + 4 * g + 2], wgt, o2);
    o3 = fmaf(p[2 + 4 * g + 3], wgt, o3);
  }
  const float inv = 1.f / L;
  float4 ov; ov.x = o0 * inv; ov.y = o1 * inv; ov.z = o2 * inv; ov.w = o3 * inv;
  *(float4*)&out[((size_t)n * TROWS + tt * TT + half * 64 + tw) * 16 + 4 * g] = ov;
}

extern "C" void kernel_launch(void* const* d_in, const int* in_sizes, int n_in,
                              void* d_out, int out_size, void* d_ws, size_t ws_size,
                              hipStream_t stream) {
  const float* ref    = (const float*)d_in[0];
  const float* tgt    = (const float*)d_in[1];
  const float* labels = (const float*)d_in[2];
  const float* wf     = (const float*)d_in[3];
  float* out = (float*)d_out;

  unsigned short* rh  = (unsigned short*)d_ws;
  unsigned short* rl  = rh + (size_t)NB * RROWS * FEAT;
  unsigned short* th  = rl + (size_t)NB * RROWS * FEAT;
  unsigned short* tl  = th + (size_t)NB * TROWS * FEAT;
  unsigned short* wth = tl + (size_t)NB * TROWS * FEAT;
  unsigned short* wtl = wth + (size_t)FEAT * FK;
  float* part = (float*)(wtl + (size_t)FEAT * FK);

  hipLaunchKernelGGL(wprep_kernel, dim3(256), dim3(192), 0, stream, wf, wth, wtl);
  hipLaunchKernelGGL(feat_kernel, dim3(512), dim3(256), 0, stream,
                     ref, tgt, wth, wtl, rh, rl, th, tl);
  hipLaunchKernelGGL(flash_kernel, dim3(8 * 8 * NCHUNK), dim3(256), 0, stream,
                     rh, rl, th, tl, labels, part);
  hipLaunchKernelGGL(combine_kernel, dim3(128), dim3(256), 0, stream,
                     part, out);
}